// Round 20
// baseline (231.258 us; speedup 1.0000x reference)
//
#include <hip/hip_runtime.h>

#define NN 200000
#define NE 3200000
#define NB_SCAN 782    // ceil(NN/256)
#define NBUCK 196      // dst buckets of 1024 nodes (dst>>10)
#define BSHIFT 10
#define BMASK 1023
#define SRCMASK 0x3FFFFu   // src fits in 18 bits (200000 < 2^18)
#define NBLK_A 512     // bucket-pass blocks
#define EPB (NE / NBLK_A)  // 6250 edges per bucket-pass block
#define NPASS 13       // src slices: src>>14
#define EMAX 18        // max edges per nsort thread

using bf16x8 = __attribute__((ext_vector_type(8))) short;
using f32x4  = __attribute__((ext_vector_type(4))) float;

__device__ __forceinline__ float bflo(unsigned u) { return __uint_as_float(u << 16); }
__device__ __forceinline__ float bfhi(unsigned u) { return __uint_as_float(u & 0xffff0000u); }
__device__ __forceinline__ unsigned short f2bfu(float f) {
  unsigned u = __float_as_uint(f);
  return (unsigned short)((u + 0x7fffu + ((u >> 16) & 1u)) >> 16);  // RNE
}
__device__ __forceinline__ unsigned pack2(float a, float b) {
  return (unsigned)f2bfu(a) | ((unsigned)f2bfu(b) << 16);
}

// accumulate one edge's 8-feature chunk into g0/g1
__device__ __forceinline__ void acc_edge(uint2 e, uint4 u, float* g0, float* g1) {
  float k0 = bflo(e.y), k1 = bfhi(e.y);
  float v0 = bflo(u.x), v1 = bfhi(u.x);
  float v2 = bflo(u.y), v3 = bfhi(u.y);
  float v4 = bflo(u.z), v5 = bfhi(u.z);
  float v6 = bflo(u.w), v7 = bfhi(u.w);
  g0[0] += k0 * v0; g0[1] += k0 * v1; g0[2] += k0 * v2; g0[3] += k0 * v3;
  g0[4] += k0 * v4; g0[5] += k0 * v5; g0[6] += k0 * v6; g0[7] += k0 * v7;
  g1[0] += k1 * v0; g1[1] += k1 * v1; g1[2] += k1 * v2; g1[3] += k1 * v3;
  g1[4] += k1 * v4; g1[5] += k1 * v5; g1[6] += k1 * v6; g1[7] += k1 * v7;
}

// ======================= stage 1: bucket sort =======================

__global__ __launch_bounds__(256) void bhist_kernel(const int* __restrict__ dst,
                                                    int* __restrict__ bhT) {
  __shared__ int h[NBUCK];
  for (int k = threadIdx.x; k < NBUCK; k += 256) h[k] = 0;
  __syncthreads();
  int base = blockIdx.x * EPB;
  for (int i = threadIdx.x; i < EPB; i += 256)
    atomicAdd(&h[dst[base + i] >> BSHIFT], 1);
  __syncthreads();
  for (int k = threadIdx.x; k < NBUCK; k += 256)
    bhT[k * NBLK_A + blockIdx.x] = h[k];
}

__global__ __launch_bounds__(NBLK_A) void bscan_kernel(int* __restrict__ bhT,
                                                       int* __restrict__ btot) {
  __shared__ int s[NBLK_A];
  int b = blockIdx.x;
  int v = bhT[b * NBLK_A + threadIdx.x];
  s[threadIdx.x] = v;
  __syncthreads();
#pragma unroll
  for (int off = 1; off < NBLK_A; off <<= 1) {
    int t = (threadIdx.x >= off) ? s[threadIdx.x - off] : 0;
    __syncthreads();
    s[threadIdx.x] += t;
    __syncthreads();
  }
  bhT[b * NBLK_A + threadIdx.x] = s[threadIdx.x] - v;  // exclusive
  if (threadIdx.x == NBLK_A - 1) btot[b] = s[NBLK_A - 1];
}

__global__ __launch_bounds__(256) void bbase_kernel(const int* __restrict__ btot,
                                                    int* __restrict__ bbase) {
  __shared__ int s[256];
  int v = (threadIdx.x < NBUCK) ? btot[threadIdx.x] : 0;
  s[threadIdx.x] = v;
  __syncthreads();
#pragma unroll
  for (int off = 1; off < 256; off <<= 1) {
    int t = (threadIdx.x >= off) ? s[threadIdx.x - off] : 0;
    __syncthreads();
    s[threadIdx.x] += t;
    __syncthreads();
  }
  if (threadIdx.x < NBUCK) bbase[threadIdx.x] = s[threadIdx.x] - v;
  if (threadIdx.x == NBUCK - 1) bbase[NBUCK] = s[threadIdx.x];
}

// bucket placement: block-local counting sort in LDS, coalesced write-out.
__global__ __launch_bounds__(256) void bplace_kernel(
    const int* __restrict__ src, const int* __restrict__ dst,
    const float* __restrict__ kw, const int* __restrict__ bhT,
    const int* __restrict__ bbase, uint2* __restrict__ bsorted) {
  __shared__ uint2 stage[EPB];                 // 50.0 KB
  __shared__ unsigned char stageK[EPB];        // 6.25 KB
  __shared__ int h[256];
  __shared__ int sc[256];
  __shared__ int gof[256];
  __shared__ int cur[256];
  int tid = threadIdx.x, blk = blockIdx.x;
  int base = blk * EPB;

  h[tid] = 0;
  __syncthreads();
  for (int i = tid; i < EPB; i += 256)
    atomicAdd(&h[dst[base + i] >> BSHIFT], 1);
  __syncthreads();
  int v = h[tid];
  sc[tid] = v;
  __syncthreads();
#pragma unroll
  for (int off = 1; off < 256; off <<= 1) {
    int t = (tid >= off) ? sc[tid - off] : 0;
    __syncthreads();
    sc[tid] += t;
    __syncthreads();
  }
  int excl = sc[tid] - v;
  cur[tid] = excl;
  if (tid < NBUCK)
    gof[tid] = bbase[tid] + bhT[tid * NBLK_A + blk] - excl;
  __syncthreads();
  for (int i = tid; i < EPB; i += 256) {
    int e = base + i;
    int d = dst[e];
    int k = d >> BSHIFT;
    int p = atomicAdd(&cur[k], 1);
    uint2 u;
    u.x = (unsigned)src[e] | ((unsigned)(d & BMASK) << 18);
    u.y = pack2(kw[e], kw[NE + e]);
    stage[p] = u;
    stageK[p] = (unsigned char)k;
  }
  __syncthreads();
  for (int i = tid; i < EPB; i += 256) {
    int k = stageK[i];
    bsorted[gof[k] + i] = stage[i];
  }
}

// ============ stage 2 fused: hist + local scan + src-sliced place ============

__global__ __launch_bounds__(1024) void nsort_kernel(
    const uint2* __restrict__ bsorted, const int* __restrict__ bbase,
    int* __restrict__ cnt, int* __restrict__ offs, uint2* __restrict__ sedge) {
  __shared__ int h[1024];
  __shared__ int cur[1024];
  int tid = threadIdx.x, b = blockIdx.x;
  h[tid] = 0;
  __syncthreads();
  int r0 = bbase[b], r1 = bbase[b + 1];
  int i0 = r0 + tid;

  uint2 e[EMAX];
#pragma unroll
  for (int j = 0; j < EMAX; ++j) {
    int i = i0 + j * 1024;
    if (i < r1) {
      e[j] = bsorted[i];
      atomicAdd(&h[e[j].x >> 18], 1);
    }
  }
  for (int i = i0 + EMAX * 1024; i < r1; i += 1024)  // overflow (statistically never)
    atomicAdd(&h[bsorted[i].x >> 18], 1);
  __syncthreads();

  int v = h[tid];
  cur[tid] = v;
  __syncthreads();
  for (int off = 1; off < 1024; off <<= 1) {
    int t = (tid >= off) ? cur[tid - off] : 0;
    __syncthreads();
    cur[tid] += t;
    __syncthreads();
  }
  int excl = r0 + cur[tid] - v;  // global exclusive offset
  int node = b * 1024 + tid;
  if (node < NN) { cnt[node] = v; offs[node] = excl; }
  __syncthreads();
  cur[tid] = excl;
  __syncthreads();

  for (int p = 0; p < NPASS; ++p) {
#pragma unroll
    for (int j = 0; j < EMAX; ++j) {
      int i = i0 + j * 1024;
      if (i < r1) {
        unsigned srcv = e[j].x & SRCMASK;
        if ((int)(srcv >> 14) == p) {
          int pos = atomicAdd(&cur[e[j].x >> 18], 1);
          uint2 w; w.x = srcv; w.y = e[j].y;
          sedge[pos] = w;
        }
      }
    }
    __syncthreads();
  }
  for (int i = i0 + EMAX * 1024; i < r1; i += 1024) {  // overflow
    uint2 u = bsorted[i];
    int pos = atomicAdd(&cur[u.x >> 18], 1);
    u.x &= SRCMASK;
    sedge[pos] = u;
  }
}

// ============== x -> bf16 table (3.2 MB, L2-resident) ==============

__global__ __launch_bounds__(256) void xcvt_kernel(const float* __restrict__ x,
                                                   unsigned short* __restrict__ xbf) {
  int i = blockIdx.x * 256 + threadIdx.x;
  if (i >= NN) return;
  const float4* xp = reinterpret_cast<const float4*>(x + (size_t)i * 8);
  float4 a = xp[0], b = xp[1];
  uint4 u;
  u.x = pack2(a.x, a.y); u.y = pack2(a.z, a.w);
  u.z = pack2(b.x, b.y); u.w = pack2(b.z, b.w);
  *reinterpret_cast<uint4*>(xbf + (size_t)i * 8) = u;
}

// ============== weight prepack: per-fragment bf16 vectors (R13-verified) ==============

__global__ __launch_bounds__(256) void wpack_kernel(
    const float* __restrict__ W1, const float* __restrict__ W2,
    unsigned short* __restrict__ W1p, unsigned short* __restrict__ W2p) {
  int t = threadIdx.x;
  {
    int n = t >> 5, lr = (t >> 1) & 15, ks = t & 1;
#pragma unroll
    for (int lg = 0; lg < 4; ++lg)
#pragma unroll
      for (int i = 0; i < 8; ++i)
        W1p[(((n * 16 + lr) * 2 + ks) * 4 + lg) * 8 + i] =
            f2bfu(W1[(size_t)(ks * 32 + lg * 8 + i) * 128 + n * 16 + lr]);
  }
  {
    int n2 = t >> 6, lr = (t >> 2) & 15, ks = t & 3;
#pragma unroll
    for (int lg = 0; lg < 4; ++lg)
#pragma unroll
      for (int i = 0; i < 8; ++i)
        W2p[(((n2 * 16 + lr) * 4 + ks) * 4 + lg) * 8 + i] =
            f2bfu(W2[(size_t)(ks * 32 + lg * 8 + i) * 64 + n2 * 16 + lr]);
  }
}

// ============== fused conv0 + mlp0 + l2norm -> h1 bf16 [N,32] ==============

__global__ __launch_bounds__(256) void fused0_kernel(
    const unsigned short* __restrict__ xbf, const int* __restrict__ offs,
    const int* __restrict__ cnt, const uint2* __restrict__ sedge,
    const float* __restrict__ W0, const float* __restrict__ b0,
    unsigned short* __restrict__ h1bf) {
  __shared__ float w0t[32][16];
  __shared__ float b0s[32];
  int tid = threadIdx.x;
  for (int i = tid; i < 16 * 32; i += 256) {
    int k = i >> 5, j = i & 31;
    w0t[j][k] = W0[i];
  }
  if (tid < 32) b0s[tid] = b0[tid];
  __syncthreads();

  int node = blockIdx.x * 256 + tid;
  if (node >= NN) return;

  int start = offs[node];
  int deg = cnt[node];
  float ha[8], hb[8];
#pragma unroll
  for (int k = 0; k < 8; ++k) { ha[k] = 0.f; hb[k] = 0.f; }

  int i = 0;
  for (; i + 4 <= deg; i += 4) {
    uint2 ee[4];
    uint4 uu[4];
#pragma unroll
    for (int j = 0; j < 4; ++j) ee[j] = sedge[start + i + j];
#pragma unroll
    for (int j = 0; j < 4; ++j)
      uu[j] = *reinterpret_cast<const uint4*>(xbf + (size_t)ee[j].x * 8);
#pragma unroll
    for (int j = 0; j < 4; ++j) acc_edge(ee[j], uu[j], ha, hb);
  }
  for (; i < deg; ++i) {
    uint2 e = sedge[start + i];
    uint4 u = *reinterpret_cast<const uint4*>(xbf + (size_t)e.x * 8);
    acc_edge(e, u, ha, hb);
  }

  float o[32];
  float ss = 0.f;
#pragma unroll
  for (int j = 0; j < 32; ++j) {
    float acc = b0s[j];
#pragma unroll
    for (int k = 0; k < 8; ++k) acc += ha[k] * w0t[j][k];
#pragma unroll
    for (int k = 0; k < 8; ++k) acc += hb[k] * w0t[j][8 + k];
    o[j] = acc;
    ss += acc * acc;
  }
  float inv = 1.f / fmaxf(sqrtf(ss), 1e-12f);
  uint4* op = reinterpret_cast<uint4*>(h1bf + (size_t)node * 32);
#pragma unroll
  for (int c = 0; c < 4; ++c) {
    uint4 u;
    u.x = pack2(o[c * 8 + 0] * inv, o[c * 8 + 1] * inv);
    u.y = pack2(o[c * 8 + 2] * inv, o[c * 8 + 3] * inv);
    u.z = pack2(o[c * 8 + 4] * inv, o[c * 8 + 5] * inv);
    u.w = pack2(o[c * 8 + 6] * inv, o[c * 8 + 7] * inv);
    op[c] = u;
  }
}

// ============== gmlp2: gather + MFMA MLP fused, wave-local, no barriers ==============
// Gather: 4 lanes/node (node=lane>>2, q=lane&3) — coalesced h1 rows, 8-deep pipeline.
// Shuffle-transpose: dest lane d gets packed g-words from src lane ((d&15)<<2)|(d>>4),
// yielding MFMA A-fragments (row=lane&15, k-chunk=lane>>4) directly in registers.
// MLP: per-wave 16-node tile, prepacked W1p/W2p fragments (L2-resident),
// wave-local hl transpose (same barrier-free pattern as mlp1 since R3).
// MFMA 16x16x32_bf16: A row=lane&15, k=(lane>>4)*8+i ; D col=lane&15, row=(lane>>4)*4+p.

__global__ __launch_bounds__(256) void gmlp2_kernel(
    const unsigned short* __restrict__ h1bf, const int* __restrict__ offs,
    const int* __restrict__ cnt, const uint2* __restrict__ sedge,
    const unsigned short* __restrict__ W1p, const float* __restrict__ b1,
    const unsigned short* __restrict__ W2p, const float* __restrict__ b2,
    float* __restrict__ out) {
  __shared__ __align__(16) short hl[4][16][136];  // 17.4 KB
  int tid = threadIdx.x;
  int wave = tid >> 6, lane = tid & 63;

  // ---- gather phase (identical math/order to R19 gather1) ----
  int nloc = lane >> 2, q = lane & 3;
  int node = blockIdx.x * 64 + wave * 16 + nloc;   // NN == 3125*64 exactly
  int start = offs[node];
  int deg = cnt[node];

  float g0[8], g1[8];
#pragma unroll
  for (int k = 0; k < 8; ++k) { g0[k] = 0.f; g1[k] = 0.f; }

  int i = 0;
  for (; i + 8 <= deg; i += 8) {
    uint2 ee[8];
    uint4 uu[8];
#pragma unroll
    for (int j = 0; j < 8; ++j) ee[j] = sedge[start + i + j];
#pragma unroll
    for (int j = 0; j < 8; ++j)
      uu[j] = *reinterpret_cast<const uint4*>(h1bf + (size_t)ee[j].x * 32 + q * 8);
#pragma unroll
    for (int j = 0; j < 8; ++j) acc_edge(ee[j], uu[j], g0, g1);
  }
  for (; i + 4 <= deg; i += 4) {
    uint2 ee[4];
    uint4 uu[4];
#pragma unroll
    for (int j = 0; j < 4; ++j) ee[j] = sedge[start + i + j];
#pragma unroll
    for (int j = 0; j < 4; ++j)
      uu[j] = *reinterpret_cast<const uint4*>(h1bf + (size_t)ee[j].x * 32 + q * 8);
#pragma unroll
    for (int j = 0; j < 4; ++j) acc_edge(ee[j], uu[j], g0, g1);
  }
  for (; i < deg; ++i) {
    uint2 e = sedge[start + i];
    uint4 u = *reinterpret_cast<const uint4*>(h1bf + (size_t)e.x * 32 + q * 8);
    acc_edge(e, u, g0, g1);
  }

  // pack to bf16 words: w[0..3] = g0 (k0-part), w[4..7] = g1 (k1-part)
  unsigned w[8];
  w[0] = pack2(g0[0], g0[1]); w[1] = pack2(g0[2], g0[3]);
  w[2] = pack2(g0[4], g0[5]); w[3] = pack2(g0[6], g0[7]);
  w[4] = pack2(g1[0], g1[1]); w[5] = pack2(g1[2], g1[3]);
  w[6] = pack2(g1[4], g1[5]); w[7] = pack2(g1[6], g1[7]);

  // shuffle transpose (16x4 grid): dest lane d <- src lane ((d&15)<<2)|(d>>4)
  int srcl = ((lane & 15) << 2) | (lane >> 4);
  union { unsigned u[4]; bf16x8 v; } fa, fb;
#pragma unroll
  for (int j = 0; j < 4; ++j) fa.u[j] = (unsigned)__shfl((int)w[j], srcl);
#pragma unroll
  for (int j = 0; j < 4; ++j) fb.u[j] = (unsigned)__shfl((int)w[4 + j], srcl);
  bf16x8 a1_0 = fa.v;   // A-fragment, K-cols 0..31 (k0-part)
  bf16x8 a1_1 = fb.v;   // A-fragment, K-cols 32..63 (k1-part)

  // ---- MFMA MLP phase (wave-local) ----
  int lr = lane & 15, lg = lane >> 4;
  float b1v[8], b2v[4];
#pragma unroll
  for (int n = 0; n < 8; ++n) b1v[n] = b1[n * 16 + lr];
#pragma unroll
  for (int n2 = 0; n2 < 4; ++n2) b2v[n2] = b2[n2 * 16 + lr];

#pragma unroll
  for (int n = 0; n < 8; ++n) {
    bf16x8 w10 = *reinterpret_cast<const bf16x8*>(
        &W1p[(((n * 16 + lr) * 2 + 0) * 4 + lg) * 8]);
    bf16x8 w11 = *reinterpret_cast<const bf16x8*>(
        &W1p[(((n * 16 + lr) * 2 + 1) * 4 + lg) * 8]);
    f32x4 acc = {0.f, 0.f, 0.f, 0.f};
    acc = __builtin_amdgcn_mfma_f32_16x16x32_bf16(a1_0, w10, acc, 0, 0, 0);
    acc = __builtin_amdgcn_mfma_f32_16x16x32_bf16(a1_1, w11, acc, 0, 0, 0);
#pragma unroll
    for (int p = 0; p < 4; ++p) {
      float v = fmaxf(acc[p] + b1v[n], 0.f);
      hl[wave][lg * 4 + p][n * 16 + lr] = (short)f2bfu(v);
    }
  }

  bf16x8 a2[4];
#pragma unroll
  for (int ks = 0; ks < 4; ++ks)
    a2[ks] = *reinterpret_cast<const bf16x8*>(&hl[wave][lr][ks * 32 + lg * 8]);
  f32x4 acc2[4];
#pragma unroll
  for (int n2 = 0; n2 < 4; ++n2) {
    f32x4 a = {0.f, 0.f, 0.f, 0.f};
#pragma unroll
    for (int ks = 0; ks < 4; ++ks) {
      bf16x8 w2 = *reinterpret_cast<const bf16x8*>(
          &W2p[(((n2 * 16 + lr) * 4 + ks) * 4 + lg) * 8]);
      a = __builtin_amdgcn_mfma_f32_16x16x32_bf16(a2[ks], w2, a, 0, 0, 0);
    }
    acc2[n2] = a;
  }

  int base = blockIdx.x * 64 + wave * 16;
#pragma unroll
  for (int p = 0; p < 4; ++p) {
    float s = 0.f;
#pragma unroll
    for (int n2 = 0; n2 < 4; ++n2) {
      float v = acc2[n2][p] + b2v[n2];
      s += v * v;
    }
    s += __shfl_xor(s, 1); s += __shfl_xor(s, 2);
    s += __shfl_xor(s, 4); s += __shfl_xor(s, 8);
    float inv = 1.f / fmaxf(sqrtf(s), 1e-12f);
    size_t rowoff = (size_t)(base + lg * 4 + p) * 64 + lr;
#pragma unroll
    for (int n2 = 0; n2 < 4; ++n2)
      out[rowoff + n2 * 16] = (acc2[n2][p] + b2v[n2]) * inv;
  }
}

// ======================= launch =======================

extern "C" void kernel_launch(void* const* d_in, const int* in_sizes, int n_in,
                              void* d_out, int out_size, void* d_ws, size_t ws_size,
                              hipStream_t stream) {
  const float* x  = (const float*)d_in[0];
  const int* ei   = (const int*)d_in[1];
  const float* kw = (const float*)d_in[2];
  const float* W0 = (const float*)d_in[3];
  const float* b0 = (const float*)d_in[4];
  const float* W1 = (const float*)d_in[5];
  const float* b1 = (const float*)d_in[6];
  const float* W2 = (const float*)d_in[7];
  const float* b2 = (const float*)d_in[8];
  float* out = (float*)d_out;

  const int* src = ei;
  const int* dst = ei + NE;

  // ws layout, ~70 MB:
  char* p = (char*)d_ws;
  uint2* bsorted = (uint2*)p;                p += (size_t)NE * 8;            // 25.6 MB
  uint2* sedge   = (uint2*)p;                p += (size_t)NE * 8;            // 25.6 MB
  unsigned short* h1bf = (unsigned short*)p; p += (size_t)NN * 32 * 2;       // 12.8 MB
  unsigned short* xbf  = (unsigned short*)p; p += (size_t)NN * 8 * 2;        // 3.2 MB
  int* bhT   = (int*)p;                      p += (size_t)NBUCK * NBLK_A * 4;// 0.4 MB
  int* btot  = (int*)p;                      p += (size_t)NBUCK * 4;
  int* bbase = (int*)p;                      p += (size_t)(NBUCK + 1) * 4;
  int* cnt   = (int*)p;                      p += (size_t)NN * 4;            // 0.8 MB
  int* offs  = (int*)p;                      p += (size_t)NN * 4;            // 0.8 MB
  unsigned short* W1p = (unsigned short*)p;  p += (size_t)8192 * 2;          // 16 KB
  unsigned short* W2p = (unsigned short*)p;  p += (size_t)8192 * 2;          // 16 KB

  wpack_kernel<<<1, 256, 0, stream>>>(W1, W2, W1p, W2p);
  xcvt_kernel<<<NB_SCAN, 256, 0, stream>>>(x, xbf);

  bhist_kernel<<<NBLK_A, 256, 0, stream>>>(dst, bhT);
  bscan_kernel<<<NBUCK, NBLK_A, 0, stream>>>(bhT, btot);
  bbase_kernel<<<1, 256, 0, stream>>>(btot, bbase);
  bplace_kernel<<<NBLK_A, 256, 0, stream>>>(src, dst, kw, bhT, bbase, bsorted);

  nsort_kernel<<<NBUCK, 1024, 0, stream>>>(bsorted, bbase, cnt, offs, sedge);

  fused0_kernel<<<NB_SCAN, 256, 0, stream>>>(xbf, offs, cnt, sedge, W0, b0, h1bf);
  gmlp2_kernel<<<NN / 64, 256, 0, stream>>>(h1bf, offs, cnt, sedge,
                                            W1p, b1, W2p, b2, out);
}

// Round 21
// 205.628 us; speedup vs baseline: 1.1246x; 1.1246x over previous
//
#include <hip/hip_runtime.h>

#define NN 200000
#define NE 3200000
#define NB_SCAN 782    // ceil(NN/256)
#define NBUCK 196      // dst buckets of 1024 nodes (dst>>10)
#define BSHIFT 10
#define BMASK 1023
#define SRCMASK 0x3FFFFu   // src fits in 18 bits (200000 < 2^18)
#define NBLK_A 512     // bucket-pass blocks
#define EPB (NE / NBLK_A)  // 6250 edges per bucket-pass block
#define NPASS 7        // src slices: src>>15 (32768-node / 2MB windows)
#define SSHIFT 15
#define EMAX 18        // max edges per nsort thread
#define NT_MLP1 12500  // NN/16 wave-tiles

using bf16x8 = __attribute__((ext_vector_type(8))) short;
using f32x4  = __attribute__((ext_vector_type(4))) float;

__device__ __forceinline__ float bflo(unsigned u) { return __uint_as_float(u << 16); }
__device__ __forceinline__ float bfhi(unsigned u) { return __uint_as_float(u & 0xffff0000u); }
__device__ __forceinline__ unsigned short f2bfu(float f) {
  unsigned u = __float_as_uint(f);
  return (unsigned short)((u + 0x7fffu + ((u >> 16) & 1u)) >> 16);  // RNE
}
__device__ __forceinline__ unsigned pack2(float a, float b) {
  return (unsigned)f2bfu(a) | ((unsigned)f2bfu(b) << 16);
}

// accumulate one edge's 8-feature chunk into g0/g1
__device__ __forceinline__ void acc_edge(uint2 e, uint4 u, float* g0, float* g1) {
  float k0 = bflo(e.y), k1 = bfhi(e.y);
  float v0 = bflo(u.x), v1 = bfhi(u.x);
  float v2 = bflo(u.y), v3 = bfhi(u.y);
  float v4 = bflo(u.z), v5 = bfhi(u.z);
  float v6 = bflo(u.w), v7 = bfhi(u.w);
  g0[0] += k0 * v0; g0[1] += k0 * v1; g0[2] += k0 * v2; g0[3] += k0 * v3;
  g0[4] += k0 * v4; g0[5] += k0 * v5; g0[6] += k0 * v6; g0[7] += k0 * v7;
  g1[0] += k1 * v0; g1[1] += k1 * v1; g1[2] += k1 * v2; g1[3] += k1 * v3;
  g1[4] += k1 * v4; g1[5] += k1 * v5; g1[6] += k1 * v6; g1[7] += k1 * v7;
}

// ======================= stage 1: bucket sort =======================

__global__ __launch_bounds__(256) void bhist_kernel(const int* __restrict__ dst,
                                                    int* __restrict__ bhT) {
  __shared__ int h[NBUCK];
  for (int k = threadIdx.x; k < NBUCK; k += 256) h[k] = 0;
  __syncthreads();
  int base = blockIdx.x * EPB;
  for (int i = threadIdx.x; i < EPB; i += 256)
    atomicAdd(&h[dst[base + i] >> BSHIFT], 1);
  __syncthreads();
  for (int k = threadIdx.x; k < NBUCK; k += 256)
    bhT[k * NBLK_A + blockIdx.x] = h[k];
}

// per-bucket exclusive scan over the NBLK_A block entries -> bhE (bhT kept)
__global__ __launch_bounds__(NBLK_A) void bscan_kernel(const int* __restrict__ bhT,
                                                       int* __restrict__ bhE,
                                                       int* __restrict__ btot) {
  __shared__ int s[NBLK_A];
  int b = blockIdx.x;
  int v = bhT[b * NBLK_A + threadIdx.x];
  s[threadIdx.x] = v;
  __syncthreads();
#pragma unroll
  for (int off = 1; off < NBLK_A; off <<= 1) {
    int t = (threadIdx.x >= off) ? s[threadIdx.x - off] : 0;
    __syncthreads();
    s[threadIdx.x] += t;
    __syncthreads();
  }
  bhE[b * NBLK_A + threadIdx.x] = s[threadIdx.x] - v;  // exclusive
  if (threadIdx.x == NBLK_A - 1) btot[b] = s[NBLK_A - 1];
}

__global__ __launch_bounds__(256) void bbase_kernel(const int* __restrict__ btot,
                                                    int* __restrict__ bbase) {
  __shared__ int s[256];
  int v = (threadIdx.x < NBUCK) ? btot[threadIdx.x] : 0;
  s[threadIdx.x] = v;
  __syncthreads();
#pragma unroll
  for (int off = 1; off < 256; off <<= 1) {
    int t = (threadIdx.x >= off) ? s[threadIdx.x - off] : 0;
    __syncthreads();
    s[threadIdx.x] += t;
    __syncthreads();
  }
  if (threadIdx.x < NBUCK) bbase[threadIdx.x] = s[threadIdx.x] - v;
  if (threadIdx.x == NBUCK - 1) bbase[NBUCK] = s[threadIdx.x];
}

// bucket placement v3: local hist loaded from bhT (no dst pre-pass),
// block-local counting sort in LDS, coalesced write-out.
__global__ __launch_bounds__(256) void bplace_kernel(
    const int* __restrict__ src, const int* __restrict__ dst,
    const float* __restrict__ kw, const int* __restrict__ bhT,
    const int* __restrict__ bhE, const int* __restrict__ bbase,
    uint2* __restrict__ bsorted) {
  __shared__ uint2 stage[EPB];                 // 50.0 KB
  __shared__ unsigned char stageK[EPB];        // 6.25 KB
  __shared__ int sc[256];
  __shared__ int hv[256];
  __shared__ int gof[256];
  __shared__ int cur[256];
  int tid = threadIdx.x, blk = blockIdx.x;
  int base = blk * EPB;

  int v = (tid < NBUCK) ? bhT[tid * NBLK_A + blk] : 0;
  hv[tid] = v;
  sc[tid] = v;
  __syncthreads();
#pragma unroll
  for (int off = 1; off < 256; off <<= 1) {
    int t = (tid >= off) ? sc[tid - off] : 0;
    __syncthreads();
    sc[tid] += t;
    __syncthreads();
  }
  int excl = sc[tid] - hv[tid];
  cur[tid] = excl;
  if (tid < NBUCK)
    gof[tid] = bbase[tid] + bhE[tid * NBLK_A + blk] - excl;
  __syncthreads();
  // place into LDS staging, bucket-sorted
  for (int i = tid; i < EPB; i += 256) {
    int e = base + i;
    int d = dst[e];
    int k = d >> BSHIFT;
    int p = atomicAdd(&cur[k], 1);
    uint2 u;
    u.x = (unsigned)src[e] | ((unsigned)(d & BMASK) << 18);
    u.y = pack2(kw[e], kw[NE + e]);
    stage[p] = u;
    stageK[p] = (unsigned char)k;
  }
  __syncthreads();
  // coalesced write-out
  for (int i = tid; i < EPB; i += 256) {
    int k = stageK[i];
    bsorted[gof[k] + i] = stage[i];
  }
}

// ============ stage 2 fused: hist + local scan + src-sliced place ============

__global__ __launch_bounds__(1024) void nsort_kernel(
    const uint2* __restrict__ bsorted, const int* __restrict__ bbase,
    int* __restrict__ cnt, int* __restrict__ offs, uint2* __restrict__ sedge) {
  __shared__ int h[1024];
  __shared__ int cur[1024];
  int tid = threadIdx.x, b = blockIdx.x;
  h[tid] = 0;
  __syncthreads();
  int r0 = bbase[b], r1 = bbase[b + 1];
  int i0 = r0 + tid;

  uint2 e[EMAX];
#pragma unroll
  for (int j = 0; j < EMAX; ++j) {
    int i = i0 + j * 1024;
    if (i < r1) {
      e[j] = bsorted[i];
      atomicAdd(&h[e[j].x >> 18], 1);
    }
  }
  for (int i = i0 + EMAX * 1024; i < r1; i += 1024)  // overflow (statistically never)
    atomicAdd(&h[bsorted[i].x >> 18], 1);
  __syncthreads();

  int v = h[tid];
  cur[tid] = v;
  __syncthreads();
  for (int off = 1; off < 1024; off <<= 1) {
    int t = (tid >= off) ? cur[tid - off] : 0;
    __syncthreads();
    cur[tid] += t;
    __syncthreads();
  }
  int excl = r0 + cur[tid] - v;  // global exclusive offset
  int node = b * 1024 + tid;
  if (node < NN) { cnt[node] = v; offs[node] = excl; }
  __syncthreads();
  cur[tid] = excl;
  __syncthreads();

  for (int p = 0; p < NPASS; ++p) {
#pragma unroll
    for (int j = 0; j < EMAX; ++j) {
      int i = i0 + j * 1024;
      if (i < r1) {
        unsigned srcv = e[j].x & SRCMASK;
        if ((int)(srcv >> SSHIFT) == p) {
          int pos = atomicAdd(&cur[e[j].x >> 18], 1);
          uint2 w; w.x = srcv; w.y = e[j].y;
          sedge[pos] = w;
        }
      }
    }
    __syncthreads();
  }
  for (int i = i0 + EMAX * 1024; i < r1; i += 1024) {  // overflow
    uint2 u = bsorted[i];
    int pos = atomicAdd(&cur[u.x >> 18], 1);
    u.x &= SRCMASK;
    sedge[pos] = u;
  }
}

// ============== x -> bf16 table (3.2 MB, L2-resident) ==============

__global__ __launch_bounds__(256) void xcvt_kernel(const float* __restrict__ x,
                                                   unsigned short* __restrict__ xbf) {
  int i = blockIdx.x * 256 + threadIdx.x;
  if (i >= NN) return;
  const float4* xp = reinterpret_cast<const float4*>(x + (size_t)i * 8);
  float4 a = xp[0], b = xp[1];
  uint4 u;
  u.x = pack2(a.x, a.y); u.y = pack2(a.z, a.w);
  u.z = pack2(b.x, b.y); u.w = pack2(b.z, b.w);
  *reinterpret_cast<uint4*>(xbf + (size_t)i * 8) = u;
}

// ============== fused conv0 + mlp0 + l2norm -> h1 bf16 [N,32] ==============

__global__ __launch_bounds__(256) void fused0_kernel(
    const unsigned short* __restrict__ xbf, const int* __restrict__ offs,
    const int* __restrict__ cnt, const uint2* __restrict__ sedge,
    const float* __restrict__ W0, const float* __restrict__ b0,
    unsigned short* __restrict__ h1bf) {
  __shared__ float w0t[32][16];
  __shared__ float b0s[32];
  int tid = threadIdx.x;
  for (int i = tid; i < 16 * 32; i += 256) {
    int k = i >> 5, j = i & 31;
    w0t[j][k] = W0[i];
  }
  if (tid < 32) b0s[tid] = b0[tid];
  __syncthreads();

  int node = blockIdx.x * 256 + tid;
  if (node >= NN) return;

  int start = offs[node];
  int deg = cnt[node];
  float ha[8], hb[8];
#pragma unroll
  for (int k = 0; k < 8; ++k) { ha[k] = 0.f; hb[k] = 0.f; }

  int i = 0;
  for (; i + 4 <= deg; i += 4) {
    uint2 ee[4];
    uint4 uu[4];
#pragma unroll
    for (int j = 0; j < 4; ++j) ee[j] = sedge[start + i + j];
#pragma unroll
    for (int j = 0; j < 4; ++j)
      uu[j] = *reinterpret_cast<const uint4*>(xbf + (size_t)ee[j].x * 8);
#pragma unroll
    for (int j = 0; j < 4; ++j) acc_edge(ee[j], uu[j], ha, hb);
  }
  for (; i < deg; ++i) {
    uint2 e = sedge[start + i];
    uint4 u = *reinterpret_cast<const uint4*>(xbf + (size_t)e.x * 8);
    acc_edge(e, u, ha, hb);
  }

  float o[32];
  float ss = 0.f;
#pragma unroll
  for (int j = 0; j < 32; ++j) {
    float acc = b0s[j];
#pragma unroll
    for (int k = 0; k < 8; ++k) acc += ha[k] * w0t[j][k];
#pragma unroll
    for (int k = 0; k < 8; ++k) acc += hb[k] * w0t[j][8 + k];
    o[j] = acc;
    ss += acc * acc;
  }
  float inv = 1.f / fmaxf(sqrtf(ss), 1e-12f);
  uint4* op = reinterpret_cast<uint4*>(h1bf + (size_t)node * 32);
#pragma unroll
  for (int c = 0; c < 4; ++c) {
    uint4 u;
    u.x = pack2(o[c * 8 + 0] * inv, o[c * 8 + 1] * inv);
    u.y = pack2(o[c * 8 + 2] * inv, o[c * 8 + 3] * inv);
    u.z = pack2(o[c * 8 + 4] * inv, o[c * 8 + 5] * inv);
    u.w = pack2(o[c * 8 + 6] * inv, o[c * 8 + 7] * inv);
    op[c] = u;
  }
}

// ============== gather1: CSR gather of h1 -> g bf16 [N,64] ==============
// 4 lanes per node; flat loop with manual 8-deep load pipeline.

__global__ __launch_bounds__(256) void gather1_kernel(
    const unsigned short* __restrict__ h1bf, const int* __restrict__ offs,
    const int* __restrict__ cnt, const uint2* __restrict__ sedge,
    unsigned short* __restrict__ gbf) {
  int idx = blockIdx.x * 256 + threadIdx.x;
  int node = idx >> 2, q = idx & 3;   // grid exact: node < NN always
  int start = offs[node];
  int deg = cnt[node];

  float g0[8], g1[8];
#pragma unroll
  for (int k = 0; k < 8; ++k) { g0[k] = 0.f; g1[k] = 0.f; }

  int i = 0;
  for (; i + 8 <= deg; i += 8) {
    uint2 ee[8];
    uint4 uu[8];
#pragma unroll
    for (int j = 0; j < 8; ++j) ee[j] = sedge[start + i + j];
#pragma unroll
    for (int j = 0; j < 8; ++j)
      uu[j] = *reinterpret_cast<const uint4*>(h1bf + (size_t)ee[j].x * 32 + q * 8);
#pragma unroll
    for (int j = 0; j < 8; ++j) acc_edge(ee[j], uu[j], g0, g1);
  }
  for (; i + 4 <= deg; i += 4) {
    uint2 ee[4];
    uint4 uu[4];
#pragma unroll
    for (int j = 0; j < 4; ++j) ee[j] = sedge[start + i + j];
#pragma unroll
    for (int j = 0; j < 4; ++j)
      uu[j] = *reinterpret_cast<const uint4*>(h1bf + (size_t)ee[j].x * 32 + q * 8);
#pragma unroll
    for (int j = 0; j < 4; ++j) acc_edge(ee[j], uu[j], g0, g1);
  }
  for (; i < deg; ++i) {
    uint2 e = sedge[start + i];
    uint4 u = *reinterpret_cast<const uint4*>(h1bf + (size_t)e.x * 32 + q * 8);
    acc_edge(e, u, g0, g1);
  }

  uint4 s0, s1;
  s0.x = pack2(g0[0], g0[1]); s0.y = pack2(g0[2], g0[3]);
  s0.z = pack2(g0[4], g0[5]); s0.w = pack2(g0[6], g0[7]);
  s1.x = pack2(g1[0], g1[1]); s1.y = pack2(g1[2], g1[3]);
  s1.z = pack2(g1[4], g1[5]); s1.w = pack2(g1[6], g1[7]);
  *reinterpret_cast<uint4*>(gbf + (size_t)node * 64 + q * 8) = s0;
  *reinterpret_cast<uint4*>(gbf + (size_t)node * 64 + 32 + q * 8) = s1;
}

// ============== mlp1: MFMA 16x16x32_bf16, 16 nodes per wave-tile ==============
// A: row=lane&15, k=(lane>>4)*8+i ; B: col=lane&15, k=(lane>>4)*8+i
// D: col=lane&15, row=(lane>>4)*4+q   [m89-verified]

__global__ __launch_bounds__(256) void mlp1_kernel(
    const unsigned short* __restrict__ gbf,
    const float* __restrict__ W1, const float* __restrict__ b1,
    const float* __restrict__ W2, const float* __restrict__ b2,
    float* __restrict__ out) {
  __shared__ __align__(16) short hlds[4][16][136];
  int tid = threadIdx.x;
  int wave = tid >> 6, lane = tid & 63;
  int lg = lane >> 4;
  int lr = lane & 15;

  bf16x8 w1f[8][2];
#pragma unroll
  for (int n = 0; n < 8; ++n)
#pragma unroll
    for (int ks = 0; ks < 2; ++ks) {
      bf16x8 f;
#pragma unroll
      for (int i = 0; i < 8; ++i)
        f[i] = (short)f2bfu(W1[(size_t)(ks * 32 + lg * 8 + i) * 128 + n * 16 + lr]);
      w1f[n][ks] = f;
    }
  bf16x8 w2f[4][4];
#pragma unroll
  for (int n2 = 0; n2 < 4; ++n2)
#pragma unroll
    for (int ks = 0; ks < 4; ++ks) {
      bf16x8 f;
#pragma unroll
      for (int i = 0; i < 8; ++i)
        f[i] = (short)f2bfu(W2[(size_t)(ks * 32 + lg * 8 + i) * 64 + n2 * 16 + lr]);
      w2f[n2][ks] = f;
    }
  float b1v[8], b2v[4];
#pragma unroll
  for (int n = 0; n < 8; ++n) b1v[n] = b1[n * 16 + lr];
#pragma unroll
  for (int n2 = 0; n2 < 4; ++n2) b2v[n2] = b2[n2 * 16 + lr];

  for (int tile = blockIdx.x * 4 + wave; tile < NT_MLP1; tile += gridDim.x * 4) {
    int base = tile * 16;
    const bf16x8* grow = reinterpret_cast<const bf16x8*>(gbf + (size_t)(base + lr) * 64);
    bf16x8 a1_0 = grow[lg];
    bf16x8 a1_1 = grow[4 + lg];

#pragma unroll
    for (int n = 0; n < 8; ++n) {
      f32x4 acc = {0.f, 0.f, 0.f, 0.f};
      acc = __builtin_amdgcn_mfma_f32_16x16x32_bf16(a1_0, w1f[n][0], acc, 0, 0, 0);
      acc = __builtin_amdgcn_mfma_f32_16x16x32_bf16(a1_1, w1f[n][1], acc, 0, 0, 0);
#pragma unroll
      for (int q = 0; q < 4; ++q) {
        float v = fmaxf(acc[q] + b1v[n], 0.f);
        hlds[wave][lg * 4 + q][n * 16 + lr] = (short)f2bfu(v);
      }
    }

    bf16x8 a2[4];
#pragma unroll
    for (int ks = 0; ks < 4; ++ks)
      a2[ks] = *reinterpret_cast<const bf16x8*>(&hlds[wave][lr][ks * 32 + lg * 8]);
    f32x4 acc2[4];
#pragma unroll
    for (int n2 = 0; n2 < 4; ++n2) {
      f32x4 a = {0.f, 0.f, 0.f, 0.f};
#pragma unroll
      for (int ks = 0; ks < 4; ++ks)
        a = __builtin_amdgcn_mfma_f32_16x16x32_bf16(a2[ks], w2f[n2][ks], a, 0, 0, 0);
      acc2[n2] = a;
    }

#pragma unroll
    for (int q = 0; q < 4; ++q) {
      float s = 0.f;
#pragma unroll
      for (int n2 = 0; n2 < 4; ++n2) {
        float v = acc2[n2][q] + b2v[n2];
        s += v * v;
      }
      s += __shfl_xor(s, 1); s += __shfl_xor(s, 2);
      s += __shfl_xor(s, 4); s += __shfl_xor(s, 8);
      float inv = 1.f / fmaxf(sqrtf(s), 1e-12f);
      size_t rowoff = (size_t)(base + lg * 4 + q) * 64 + lr;
#pragma unroll
      for (int n2 = 0; n2 < 4; ++n2)
        out[rowoff + n2 * 16] = (acc2[n2][q] + b2v[n2]) * inv;
    }
  }
}

// ======================= launch =======================

extern "C" void kernel_launch(void* const* d_in, const int* in_sizes, int n_in,
                              void* d_out, int out_size, void* d_ws, size_t ws_size,
                              hipStream_t stream) {
  const float* x  = (const float*)d_in[0];
  const int* ei   = (const int*)d_in[1];
  const float* kw = (const float*)d_in[2];
  const float* W0 = (const float*)d_in[3];
  const float* b0 = (const float*)d_in[4];
  const float* W1 = (const float*)d_in[5];
  const float* b1 = (const float*)d_in[6];
  const float* W2 = (const float*)d_in[7];
  const float* b2 = (const float*)d_in[8];
  float* out = (float*)d_out;

  const int* src = ei;
  const int* dst = ei + NE;

  // ws layout, ~70 MB:
  char* p = (char*)d_ws;
  uint2* bsorted = (uint2*)p;                p += (size_t)NE * 8;            // 25.6 MB
  uint2* sedge   = (uint2*)p;                p += (size_t)NE * 8;            // 25.6 MB
  unsigned short* h1bf = (unsigned short*)p; p += (size_t)NN * 32 * 2;       // 12.8 MB
  unsigned short* xbf  = (unsigned short*)p; p += (size_t)NN * 8 * 2;        // 3.2 MB
  int* bhT   = (int*)p;                      p += (size_t)NBUCK * NBLK_A * 4;// 0.4 MB
  int* bhE   = (int*)p;                      p += (size_t)NBUCK * NBLK_A * 4;// 0.4 MB
  int* btot  = (int*)p;                      p += (size_t)NBUCK * 4;
  int* bbase = (int*)p;                      p += (size_t)(NBUCK + 1) * 4;
  int* cnt   = (int*)p;                      p += (size_t)NN * 4;            // 0.8 MB
  int* offs  = (int*)p;                      p += (size_t)NN * 4;            // 0.8 MB
  // gbf reuses bsorted (dead after nsort); NN*64*2 == NE*8 bytes exactly.
  unsigned short* gbf = (unsigned short*)bsorted;

  xcvt_kernel<<<NB_SCAN, 256, 0, stream>>>(x, xbf);

  bhist_kernel<<<NBLK_A, 256, 0, stream>>>(dst, bhT);
  bscan_kernel<<<NBUCK, NBLK_A, 0, stream>>>(bhT, bhE, btot);
  bbase_kernel<<<1, 256, 0, stream>>>(btot, bbase);
  bplace_kernel<<<NBLK_A, 256, 0, stream>>>(src, dst, kw, bhT, bhE, bbase, bsorted);

  nsort_kernel<<<NBUCK, 1024, 0, stream>>>(bsorted, bbase, cnt, offs, sedge);

  fused0_kernel<<<NB_SCAN, 256, 0, stream>>>(xbf, offs, cnt, sedge, W0, b0, h1bf);
  gather1_kernel<<<(4 * NN) / 256, 256, 0, stream>>>(h1bf, offs, cnt, sedge, gbf);
  mlp1_kernel<<<768, 256, 0, stream>>>(gbf, W1, b1, W2, b2, out);
}

// Round 22
// 203.362 us; speedup vs baseline: 1.1372x; 1.0111x over previous
//
#include <hip/hip_runtime.h>

#define NN 200000
#define NE 3200000
#define NB_SCAN 782    // ceil(NN/256)
#define NBUCK 391      // dst buckets of 512 nodes (dst>>9); 199999>>9 = 390
#define BSHIFT 9
#define BMASK 511
#define SRCMASK 0x3FFFFu   // src fits in 18 bits (200000 < 2^18)
#define NBLK_A 1024    // bucket-pass blocks
#define EPB (NE / NBLK_A)  // 3125 edges per bucket-pass block
#define NPASS 7        // src slices: src>>15 (2MB h1 windows)
#define SSHIFT 15
#define EMAX 18        // max edges per nsort thread (bucket<=~8600, /512=16.8)
#define NT_MLP1 12500  // NN/16 wave-tiles

using bf16x8 = __attribute__((ext_vector_type(8))) short;
using f32x4  = __attribute__((ext_vector_type(4))) float;

__device__ __forceinline__ float bflo(unsigned u) { return __uint_as_float(u << 16); }
__device__ __forceinline__ float bfhi(unsigned u) { return __uint_as_float(u & 0xffff0000u); }
__device__ __forceinline__ unsigned short f2bfu(float f) {
  unsigned u = __float_as_uint(f);
  return (unsigned short)((u + 0x7fffu + ((u >> 16) & 1u)) >> 16);  // RNE
}
__device__ __forceinline__ unsigned pack2(float a, float b) {
  return (unsigned)f2bfu(a) | ((unsigned)f2bfu(b) << 16);
}

// accumulate one edge's 8-feature chunk into g0/g1
__device__ __forceinline__ void acc_edge(uint2 e, uint4 u, float* g0, float* g1) {
  float k0 = bflo(e.y), k1 = bfhi(e.y);
  float v0 = bflo(u.x), v1 = bfhi(u.x);
  float v2 = bflo(u.y), v3 = bfhi(u.y);
  float v4 = bflo(u.z), v5 = bfhi(u.z);
  float v6 = bflo(u.w), v7 = bfhi(u.w);
  g0[0] += k0 * v0; g0[1] += k0 * v1; g0[2] += k0 * v2; g0[3] += k0 * v3;
  g0[4] += k0 * v4; g0[5] += k0 * v5; g0[6] += k0 * v6; g0[7] += k0 * v7;
  g1[0] += k1 * v0; g1[1] += k1 * v1; g1[2] += k1 * v2; g1[3] += k1 * v3;
  g1[4] += k1 * v4; g1[5] += k1 * v5; g1[6] += k1 * v6; g1[7] += k1 * v7;
}

// ======================= stage 1: bucket sort =======================

__global__ __launch_bounds__(256) void bhist_kernel(const int* __restrict__ dst,
                                                    int* __restrict__ bhT) {
  __shared__ int h[NBUCK];
  for (int k = threadIdx.x; k < NBUCK; k += 256) h[k] = 0;
  __syncthreads();
  int base = blockIdx.x * EPB;
  for (int i = threadIdx.x; i < EPB; i += 256)
    atomicAdd(&h[dst[base + i] >> BSHIFT], 1);
  __syncthreads();
  for (int k = threadIdx.x; k < NBUCK; k += 256)
    bhT[k * NBLK_A + blockIdx.x] = h[k];
}

// per-bucket exclusive scan over the NBLK_A block entries -> bhE (bhT kept)
__global__ __launch_bounds__(NBLK_A) void bscan_kernel(const int* __restrict__ bhT,
                                                       int* __restrict__ bhE,
                                                       int* __restrict__ btot) {
  __shared__ int s[NBLK_A];
  int b = blockIdx.x;
  int v = bhT[b * NBLK_A + threadIdx.x];
  s[threadIdx.x] = v;
  __syncthreads();
#pragma unroll
  for (int off = 1; off < NBLK_A; off <<= 1) {
    int t = (threadIdx.x >= off) ? s[threadIdx.x - off] : 0;
    __syncthreads();
    s[threadIdx.x] += t;
    __syncthreads();
  }
  bhE[b * NBLK_A + threadIdx.x] = s[threadIdx.x] - v;  // exclusive
  if (threadIdx.x == NBLK_A - 1) btot[b] = s[NBLK_A - 1];
}

// exclusive scan of btot[NBUCK] -> bbase[NBUCK+1]  (512-wide)
__global__ __launch_bounds__(512) void bbase_kernel(const int* __restrict__ btot,
                                                    int* __restrict__ bbase) {
  __shared__ int s[512];
  int v = (threadIdx.x < NBUCK) ? btot[threadIdx.x] : 0;
  s[threadIdx.x] = v;
  __syncthreads();
#pragma unroll
  for (int off = 1; off < 512; off <<= 1) {
    int t = (threadIdx.x >= off) ? s[threadIdx.x - off] : 0;
    __syncthreads();
    s[threadIdx.x] += t;
    __syncthreads();
  }
  if (threadIdx.x < NBUCK) bbase[threadIdx.x] = s[threadIdx.x] - v;
  if (threadIdx.x == NBUCK - 1) bbase[NBUCK] = s[threadIdx.x];
}

// bucket placement: local hist from bhT, LDS counting sort, coalesced write-out.
// 512 threads; bins (391) < 512-wide scan; stage 25KB -> ~4 blocks/CU.
__global__ __launch_bounds__(512) void bplace_kernel(
    const int* __restrict__ src, const int* __restrict__ dst,
    const float* __restrict__ kw, const int* __restrict__ bhT,
    const int* __restrict__ bhE, const int* __restrict__ bbase,
    uint2* __restrict__ bsorted) {
  __shared__ uint2 stage[EPB];                 // 25.0 KB
  __shared__ unsigned short stageK[EPB];       // 6.25 KB
  __shared__ int sc[512];
  __shared__ int hv[512];
  __shared__ int gof[512];
  __shared__ int cur[512];
  int tid = threadIdx.x, blk = blockIdx.x;
  int base = blk * EPB;

  int v = (tid < NBUCK) ? bhT[tid * NBLK_A + blk] : 0;
  hv[tid] = v;
  sc[tid] = v;
  __syncthreads();
#pragma unroll
  for (int off = 1; off < 512; off <<= 1) {
    int t = (tid >= off) ? sc[tid - off] : 0;
    __syncthreads();
    sc[tid] += t;
    __syncthreads();
  }
  int excl = sc[tid] - hv[tid];
  cur[tid] = excl;
  if (tid < NBUCK)
    gof[tid] = bbase[tid] + bhE[tid * NBLK_A + blk] - excl;
  __syncthreads();
  // place into LDS staging, bucket-sorted
  for (int i = tid; i < EPB; i += 512) {
    int e = base + i;
    int d = dst[e];
    int k = d >> BSHIFT;
    int p = atomicAdd(&cur[k], 1);
    uint2 u;
    u.x = (unsigned)src[e] | ((unsigned)(d & BMASK) << 18);
    u.y = pack2(kw[e], kw[NE + e]);
    stage[p] = u;
    stageK[p] = (unsigned short)k;
  }
  __syncthreads();
  // coalesced write-out (consecutive i -> consecutive addrs within chunks)
  for (int i = tid; i < EPB; i += 512) {
    int k = stageK[i];
    bsorted[gof[k] + i] = stage[i];
  }
}

// ============ stage 2 fused: hist + local scan + src-sliced place ============
// 391 blocks x 512 threads (512 nodes/bucket).

__global__ __launch_bounds__(512) void nsort_kernel(
    const uint2* __restrict__ bsorted, const int* __restrict__ bbase,
    int* __restrict__ cnt, int* __restrict__ offs, uint2* __restrict__ sedge) {
  __shared__ int h[512];
  __shared__ int cur[512];
  int tid = threadIdx.x, b = blockIdx.x;
  h[tid] = 0;
  __syncthreads();
  int r0 = bbase[b], r1 = bbase[b + 1];
  int i0 = r0 + tid;

  uint2 e[EMAX];
#pragma unroll
  for (int j = 0; j < EMAX; ++j) {
    int i = i0 + j * 512;
    if (i < r1) {
      e[j] = bsorted[i];
      atomicAdd(&h[e[j].x >> 18], 1);
    }
  }
  for (int i = i0 + EMAX * 512; i < r1; i += 512)  // overflow (statistically never)
    atomicAdd(&h[bsorted[i].x >> 18], 1);
  __syncthreads();

  int v = h[tid];
  cur[tid] = v;
  __syncthreads();
#pragma unroll
  for (int off = 1; off < 512; off <<= 1) {
    int t = (tid >= off) ? cur[tid - off] : 0;
    __syncthreads();
    cur[tid] += t;
    __syncthreads();
  }
  int excl = r0 + cur[tid] - v;  // global exclusive offset
  int node = b * 512 + tid;
  if (node < NN) { cnt[node] = v; offs[node] = excl; }
  __syncthreads();
  cur[tid] = excl;
  __syncthreads();

  for (int p = 0; p < NPASS; ++p) {
#pragma unroll
    for (int j = 0; j < EMAX; ++j) {
      int i = i0 + j * 512;
      if (i < r1) {
        unsigned srcv = e[j].x & SRCMASK;
        if ((int)(srcv >> SSHIFT) == p) {
          int pos = atomicAdd(&cur[e[j].x >> 18], 1);
          uint2 w; w.x = srcv; w.y = e[j].y;
          sedge[pos] = w;
        }
      }
    }
    __syncthreads();
  }
  for (int i = i0 + EMAX * 512; i < r1; i += 512) {  // overflow
    uint2 u = bsorted[i];
    int pos = atomicAdd(&cur[u.x >> 18], 1);
    u.x &= SRCMASK;
    sedge[pos] = u;
  }
}

// ============== x -> bf16 table (3.2 MB, L2-resident) ==============

__global__ __launch_bounds__(256) void xcvt_kernel(const float* __restrict__ x,
                                                   unsigned short* __restrict__ xbf) {
  int i = blockIdx.x * 256 + threadIdx.x;
  if (i >= NN) return;
  const float4* xp = reinterpret_cast<const float4*>(x + (size_t)i * 8);
  float4 a = xp[0], b = xp[1];
  uint4 u;
  u.x = pack2(a.x, a.y); u.y = pack2(a.z, a.w);
  u.z = pack2(b.x, b.y); u.w = pack2(b.z, b.w);
  *reinterpret_cast<uint4*>(xbf + (size_t)i * 8) = u;
}

// ============== fused conv0 + mlp0 + l2norm -> h1 bf16 [N,32] ==============

__global__ __launch_bounds__(256) void fused0_kernel(
    const unsigned short* __restrict__ xbf, const int* __restrict__ offs,
    const int* __restrict__ cnt, const uint2* __restrict__ sedge,
    const float* __restrict__ W0, const float* __restrict__ b0,
    unsigned short* __restrict__ h1bf) {
  __shared__ float w0t[32][16];
  __shared__ float b0s[32];
  int tid = threadIdx.x;
  for (int i = tid; i < 16 * 32; i += 256) {
    int k = i >> 5, j = i & 31;
    w0t[j][k] = W0[i];
  }
  if (tid < 32) b0s[tid] = b0[tid];
  __syncthreads();

  int node = blockIdx.x * 256 + tid;
  if (node >= NN) return;

  int start = offs[node];
  int deg = cnt[node];
  float ha[8], hb[8];
#pragma unroll
  for (int k = 0; k < 8; ++k) { ha[k] = 0.f; hb[k] = 0.f; }

  int i = 0;
  for (; i + 4 <= deg; i += 4) {
    uint2 ee[4];
    uint4 uu[4];
#pragma unroll
    for (int j = 0; j < 4; ++j) ee[j] = sedge[start + i + j];
#pragma unroll
    for (int j = 0; j < 4; ++j)
      uu[j] = *reinterpret_cast<const uint4*>(xbf + (size_t)ee[j].x * 8);
#pragma unroll
    for (int j = 0; j < 4; ++j) acc_edge(ee[j], uu[j], ha, hb);
  }
  for (; i < deg; ++i) {
    uint2 e = sedge[start + i];
    uint4 u = *reinterpret_cast<const uint4*>(xbf + (size_t)e.x * 8);
    acc_edge(e, u, ha, hb);
  }

  float o[32];
  float ss = 0.f;
#pragma unroll
  for (int j = 0; j < 32; ++j) {
    float acc = b0s[j];
#pragma unroll
    for (int k = 0; k < 8; ++k) acc += ha[k] * w0t[j][k];
#pragma unroll
    for (int k = 0; k < 8; ++k) acc += hb[k] * w0t[j][8 + k];
    o[j] = acc;
    ss += acc * acc;
  }
  float inv = 1.f / fmaxf(sqrtf(ss), 1e-12f);
  uint4* op = reinterpret_cast<uint4*>(h1bf + (size_t)node * 32);
#pragma unroll
  for (int c = 0; c < 4; ++c) {
    uint4 u;
    u.x = pack2(o[c * 8 + 0] * inv, o[c * 8 + 1] * inv);
    u.y = pack2(o[c * 8 + 2] * inv, o[c * 8 + 3] * inv);
    u.z = pack2(o[c * 8 + 4] * inv, o[c * 8 + 5] * inv);
    u.w = pack2(o[c * 8 + 6] * inv, o[c * 8 + 7] * inv);
    op[c] = u;
  }
}

// ============== gather1: CSR gather of h1 -> g bf16 [N,64] ==============
// 4 lanes per node; flat loop with manual 8-deep load pipeline.

__global__ __launch_bounds__(256) void gather1_kernel(
    const unsigned short* __restrict__ h1bf, const int* __restrict__ offs,
    const int* __restrict__ cnt, const uint2* __restrict__ sedge,
    unsigned short* __restrict__ gbf) {
  int idx = blockIdx.x * 256 + threadIdx.x;
  int node = idx >> 2, q = idx & 3;   // grid exact: node < NN always
  int start = offs[node];
  int deg = cnt[node];

  float g0[8], g1[8];
#pragma unroll
  for (int k = 0; k < 8; ++k) { g0[k] = 0.f; g1[k] = 0.f; }

  int i = 0;
  for (; i + 8 <= deg; i += 8) {
    uint2 ee[8];
    uint4 uu[8];
#pragma unroll
    for (int j = 0; j < 8; ++j) ee[j] = sedge[start + i + j];
#pragma unroll
    for (int j = 0; j < 8; ++j)
      uu[j] = *reinterpret_cast<const uint4*>(h1bf + (size_t)ee[j].x * 32 + q * 8);
#pragma unroll
    for (int j = 0; j < 8; ++j) acc_edge(ee[j], uu[j], g0, g1);
  }
  for (; i + 4 <= deg; i += 4) {
    uint2 ee[4];
    uint4 uu[4];
#pragma unroll
    for (int j = 0; j < 4; ++j) ee[j] = sedge[start + i + j];
#pragma unroll
    for (int j = 0; j < 4; ++j)
      uu[j] = *reinterpret_cast<const uint4*>(h1bf + (size_t)ee[j].x * 32 + q * 8);
#pragma unroll
    for (int j = 0; j < 4; ++j) acc_edge(ee[j], uu[j], g0, g1);
  }
  for (; i < deg; ++i) {
    uint2 e = sedge[start + i];
    uint4 u = *reinterpret_cast<const uint4*>(h1bf + (size_t)e.x * 32 + q * 8);
    acc_edge(e, u, g0, g1);
  }

  uint4 s0, s1;
  s0.x = pack2(g0[0], g0[1]); s0.y = pack2(g0[2], g0[3]);
  s0.z = pack2(g0[4], g0[5]); s0.w = pack2(g0[6], g0[7]);
  s1.x = pack2(g1[0], g1[1]); s1.y = pack2(g1[2], g1[3]);
  s1.z = pack2(g1[4], g1[5]); s1.w = pack2(g1[6], g1[7]);
  *reinterpret_cast<uint4*>(gbf + (size_t)node * 64 + q * 8) = s0;
  *reinterpret_cast<uint4*>(gbf + (size_t)node * 64 + 32 + q * 8) = s1;
}

// ============== mlp1: MFMA 16x16x32_bf16, 16 nodes per wave-tile ==============
// A: row=lane&15, k=(lane>>4)*8+i ; B: col=lane&15, k=(lane>>4)*8+i
// D: col=lane&15, row=(lane>>4)*4+q   [m89-verified]

__global__ __launch_bounds__(256) void mlp1_kernel(
    const unsigned short* __restrict__ gbf,
    const float* __restrict__ W1, const float* __restrict__ b1,
    const float* __restrict__ W2, const float* __restrict__ b2,
    float* __restrict__ out) {
  __shared__ __align__(16) short hlds[4][16][136];
  int tid = threadIdx.x;
  int wave = tid >> 6, lane = tid & 63;
  int lg = lane >> 4;
  int lr = lane & 15;

  bf16x8 w1f[8][2];
#pragma unroll
  for (int n = 0; n < 8; ++n)
#pragma unroll
    for (int ks = 0; ks < 2; ++ks) {
      bf16x8 f;
#pragma unroll
      for (int i = 0; i < 8; ++i)
        f[i] = (short)f2bfu(W1[(size_t)(ks * 32 + lg * 8 + i) * 128 + n * 16 + lr]);
      w1f[n][ks] = f;
    }
  bf16x8 w2f[4][4];
#pragma unroll
  for (int n2 = 0; n2 < 4; ++n2)
#pragma unroll
    for (int ks = 0; ks < 4; ++ks) {
      bf16x8 f;
#pragma unroll
      for (int i = 0; i < 8; ++i)
        f[i] = (short)f2bfu(W2[(size_t)(ks * 32 + lg * 8 + i) * 64 + n2 * 16 + lr]);
      w2f[n2][ks] = f;
    }
  float b1v[8], b2v[4];
#pragma unroll
  for (int n = 0; n < 8; ++n) b1v[n] = b1[n * 16 + lr];
#pragma unroll
  for (int n2 = 0; n2 < 4; ++n2) b2v[n2] = b2[n2 * 16 + lr];

  for (int tile = blockIdx.x * 4 + wave; tile < NT_MLP1; tile += gridDim.x * 4) {
    int base = tile * 16;
    const bf16x8* grow = reinterpret_cast<const bf16x8*>(gbf + (size_t)(base + lr) * 64);
    bf16x8 a1_0 = grow[lg];
    bf16x8 a1_1 = grow[4 + lg];

#pragma unroll
    for (int n = 0; n < 8; ++n) {
      f32x4 acc = {0.f, 0.f, 0.f, 0.f};
      acc = __builtin_amdgcn_mfma_f32_16x16x32_bf16(a1_0, w1f[n][0], acc, 0, 0, 0);
      acc = __builtin_amdgcn_mfma_f32_16x16x32_bf16(a1_1, w1f[n][1], acc, 0, 0, 0);
#pragma unroll
      for (int q = 0; q < 4; ++q) {
        float v = fmaxf(acc[q] + b1v[n], 0.f);
        hlds[wave][lg * 4 + q][n * 16 + lr] = (short)f2bfu(v);
      }
    }

    bf16x8 a2[4];
#pragma unroll
    for (int ks = 0; ks < 4; ++ks)
      a2[ks] = *reinterpret_cast<const bf16x8*>(&hlds[wave][lr][ks * 32 + lg * 8]);
    f32x4 acc2[4];
#pragma unroll
    for (int n2 = 0; n2 < 4; ++n2) {
      f32x4 a = {0.f, 0.f, 0.f, 0.f};
#pragma unroll
      for (int ks = 0; ks < 4; ++ks)
        a = __builtin_amdgcn_mfma_f32_16x16x32_bf16(a2[ks], w2f[n2][ks], a, 0, 0, 0);
      acc2[n2] = a;
    }

#pragma unroll
    for (int q = 0; q < 4; ++q) {
      float s = 0.f;
#pragma unroll
      for (int n2 = 0; n2 < 4; ++n2) {
        float v = acc2[n2][q] + b2v[n2];
        s += v * v;
      }
      s += __shfl_xor(s, 1); s += __shfl_xor(s, 2);
      s += __shfl_xor(s, 4); s += __shfl_xor(s, 8);
      float inv = 1.f / fmaxf(sqrtf(s), 1e-12f);
      size_t rowoff = (size_t)(base + lg * 4 + q) * 64 + lr;
#pragma unroll
      for (int n2 = 0; n2 < 4; ++n2)
        out[rowoff + n2 * 16] = (acc2[n2][q] + b2v[n2]) * inv;
    }
  }
}

// ======================= launch =======================

extern "C" void kernel_launch(void* const* d_in, const int* in_sizes, int n_in,
                              void* d_out, int out_size, void* d_ws, size_t ws_size,
                              hipStream_t stream) {
  const float* x  = (const float*)d_in[0];
  const int* ei   = (const int*)d_in[1];
  const float* kw = (const float*)d_in[2];
  const float* W0 = (const float*)d_in[3];
  const float* b0 = (const float*)d_in[4];
  const float* W1 = (const float*)d_in[5];
  const float* b1 = (const float*)d_in[6];
  const float* W2 = (const float*)d_in[7];
  const float* b2 = (const float*)d_in[8];
  float* out = (float*)d_out;

  const int* src = ei;
  const int* dst = ei + NE;

  // ws layout, ~72 MB:
  char* p = (char*)d_ws;
  uint2* bsorted = (uint2*)p;                p += (size_t)NE * 8;            // 25.6 MB
  uint2* sedge   = (uint2*)p;                p += (size_t)NE * 8;            // 25.6 MB
  unsigned short* h1bf = (unsigned short*)p; p += (size_t)NN * 32 * 2;       // 12.8 MB
  unsigned short* xbf  = (unsigned short*)p; p += (size_t)NN * 8 * 2;        // 3.2 MB
  int* bhT   = (int*)p;                      p += (size_t)NBUCK * NBLK_A * 4;// 1.6 MB
  int* bhE   = (int*)p;                      p += (size_t)NBUCK * NBLK_A * 4;// 1.6 MB
  int* btot  = (int*)p;                      p += (size_t)NBUCK * 4;
  int* bbase = (int*)p;                      p += (size_t)(NBUCK + 1) * 4;
  int* cnt   = (int*)p;                      p += (size_t)NN * 4;            // 0.8 MB
  int* offs  = (int*)p;                      p += (size_t)NN * 4;            // 0.8 MB
  // gbf reuses bsorted (dead after nsort); NN*64*2 == NE*8 bytes exactly.
  unsigned short* gbf = (unsigned short*)bsorted;

  xcvt_kernel<<<NB_SCAN, 256, 0, stream>>>(x, xbf);

  bhist_kernel<<<NBLK_A, 256, 0, stream>>>(dst, bhT);
  bscan_kernel<<<NBUCK, NBLK_A, 0, stream>>>(bhT, bhE, btot);
  bbase_kernel<<<1, 512, 0, stream>>>(btot, bbase);
  bplace_kernel<<<NBLK_A, 512, 0, stream>>>(src, dst, kw, bhT, bhE, bbase, bsorted);

  nsort_kernel<<<NBUCK, 512, 0, stream>>>(bsorted, bbase, cnt, offs, sedge);

  fused0_kernel<<<NB_SCAN, 256, 0, stream>>>(xbf, offs, cnt, sedge, W0, b0, h1bf);
  gather1_kernel<<<(4 * NN) / 256, 256, 0, stream>>>(h1bf, offs, cnt, sedge, gbf);
  mlp1_kernel<<<768, 256, 0, stream>>>(gbf, W1, b1, W2, b2, out);
}

// Round 23
// 202.953 us; speedup vs baseline: 1.1395x; 1.0020x over previous
//
#include <hip/hip_runtime.h>

#define NN 200000
#define NE 3200000
#define NB_SCAN 782    // ceil(NN/256)
#define NBUCK 391      // dst buckets of 512 nodes (dst>>9)
#define BSHIFT 9
#define BMASK 511
#define SRCMASK 0x3FFFFu   // src fits in 18 bits (200000 < 2^18)
#define NBLK_A 1024    // bucket-pass blocks
#define EPB (NE / NBLK_A)  // 3125 edges per bucket-pass block
#define SSHIFT 15      // src slice = src>>15, values 0..6 (3 bits)
#define EMAX 18        // max edges per nsort thread (bucket max ~8545, /512 = 16.7)
#define NT_MLP1 12500  // NN/16 wave-tiles

using bf16x8 = __attribute__((ext_vector_type(8))) short;
using f32x4  = __attribute__((ext_vector_type(4))) float;

__device__ __forceinline__ float bflo(unsigned u) { return __uint_as_float(u << 16); }
__device__ __forceinline__ float bfhi(unsigned u) { return __uint_as_float(u & 0xffff0000u); }
__device__ __forceinline__ unsigned short f2bfu(float f) {
  unsigned u = __float_as_uint(f);
  return (unsigned short)((u + 0x7fffu + ((u >> 16) & 1u)) >> 16);  // RNE
}
__device__ __forceinline__ unsigned pack2(float a, float b) {
  return (unsigned)f2bfu(a) | ((unsigned)f2bfu(b) << 16);
}

// accumulate one edge's 8-feature chunk into g0/g1
__device__ __forceinline__ void acc_edge(uint2 e, uint4 u, float* g0, float* g1) {
  float k0 = bflo(e.y), k1 = bfhi(e.y);
  float v0 = bflo(u.x), v1 = bfhi(u.x);
  float v2 = bflo(u.y), v3 = bfhi(u.y);
  float v4 = bflo(u.z), v5 = bfhi(u.z);
  float v6 = bflo(u.w), v7 = bfhi(u.w);
  g0[0] += k0 * v0; g0[1] += k0 * v1; g0[2] += k0 * v2; g0[3] += k0 * v3;
  g0[4] += k0 * v4; g0[5] += k0 * v5; g0[6] += k0 * v6; g0[7] += k0 * v7;
  g1[0] += k1 * v0; g1[1] += k1 * v1; g1[2] += k1 * v2; g1[3] += k1 * v3;
  g1[4] += k1 * v4; g1[5] += k1 * v5; g1[6] += k1 * v6; g1[7] += k1 * v7;
}

// ======================= stage 1: bucket sort =======================
// bhist also performs the x->bf16 conversion (xcvt folded in: free VALU work
// inside an LDS-atomic-bound kernel; grid 1024x256 covers NN exactly once).

__global__ __launch_bounds__(256) void bhist_kernel(const int* __restrict__ dst,
                                                    int* __restrict__ bhT,
                                                    const float* __restrict__ x,
                                                    unsigned short* __restrict__ xbf) {
  __shared__ int h[NBUCK];
  for (int k = threadIdx.x; k < NBUCK; k += 256) h[k] = 0;
  __syncthreads();

  // folded xcvt: one node per thread (1024*256 = 262144 >= NN)
  int nid = blockIdx.x * 256 + threadIdx.x;
  if (nid < NN) {
    const float4* xp = reinterpret_cast<const float4*>(x + (size_t)nid * 8);
    float4 a = xp[0], b = xp[1];
    uint4 u;
    u.x = pack2(a.x, a.y); u.y = pack2(a.z, a.w);
    u.z = pack2(b.x, b.y); u.w = pack2(b.z, b.w);
    *reinterpret_cast<uint4*>(xbf + (size_t)nid * 8) = u;
  }

  int base = blockIdx.x * EPB;
  for (int i = threadIdx.x; i < EPB; i += 256)
    atomicAdd(&h[dst[base + i] >> BSHIFT], 1);
  __syncthreads();
  for (int k = threadIdx.x; k < NBUCK; k += 256)
    bhT[k * NBLK_A + blockIdx.x] = h[k];
}

// per-bucket exclusive scan over the NBLK_A block entries -> bhE (bhT kept)
__global__ __launch_bounds__(NBLK_A) void bscan_kernel(const int* __restrict__ bhT,
                                                       int* __restrict__ bhE,
                                                       int* __restrict__ btot) {
  __shared__ int s[NBLK_A];
  int b = blockIdx.x;
  int v = bhT[b * NBLK_A + threadIdx.x];
  s[threadIdx.x] = v;
  __syncthreads();
#pragma unroll
  for (int off = 1; off < NBLK_A; off <<= 1) {
    int t = (threadIdx.x >= off) ? s[threadIdx.x - off] : 0;
    __syncthreads();
    s[threadIdx.x] += t;
    __syncthreads();
  }
  bhE[b * NBLK_A + threadIdx.x] = s[threadIdx.x] - v;  // exclusive
  if (threadIdx.x == NBLK_A - 1) btot[b] = s[NBLK_A - 1];
}

// exclusive scan of btot[NBUCK] -> bbase[NBUCK+1]  (512-wide)
__global__ __launch_bounds__(512) void bbase_kernel(const int* __restrict__ btot,
                                                    int* __restrict__ bbase) {
  __shared__ int s[512];
  int v = (threadIdx.x < NBUCK) ? btot[threadIdx.x] : 0;
  s[threadIdx.x] = v;
  __syncthreads();
#pragma unroll
  for (int off = 1; off < 512; off <<= 1) {
    int t = (threadIdx.x >= off) ? s[threadIdx.x - off] : 0;
    __syncthreads();
    s[threadIdx.x] += t;
    __syncthreads();
  }
  if (threadIdx.x < NBUCK) bbase[threadIdx.x] = s[threadIdx.x] - v;
  if (threadIdx.x == NBUCK - 1) bbase[NBUCK] = s[threadIdx.x];
}

// bucket placement: local hist from bhT, LDS counting sort, coalesced write-out.
__global__ __launch_bounds__(512) void bplace_kernel(
    const int* __restrict__ src, const int* __restrict__ dst,
    const float* __restrict__ kw, const int* __restrict__ bhT,
    const int* __restrict__ bhE, const int* __restrict__ bbase,
    uint2* __restrict__ bsorted) {
  __shared__ uint2 stage[EPB];                 // 25.0 KB
  __shared__ unsigned short stageK[EPB];       // 6.25 KB
  __shared__ int sc[512];
  __shared__ int hv[512];
  __shared__ int gof[512];
  __shared__ int cur[512];
  int tid = threadIdx.x, blk = blockIdx.x;
  int base = blk * EPB;

  int v = (tid < NBUCK) ? bhT[tid * NBLK_A + blk] : 0;
  hv[tid] = v;
  sc[tid] = v;
  __syncthreads();
#pragma unroll
  for (int off = 1; off < 512; off <<= 1) {
    int t = (tid >= off) ? sc[tid - off] : 0;
    __syncthreads();
    sc[tid] += t;
    __syncthreads();
  }
  int excl = sc[tid] - hv[tid];
  cur[tid] = excl;
  if (tid < NBUCK)
    gof[tid] = bbase[tid] + bhE[tid * NBLK_A + blk] - excl;
  __syncthreads();
  // place into LDS staging, bucket-sorted
  for (int i = tid; i < EPB; i += 512) {
    int e = base + i;
    int d = dst[e];
    int k = d >> BSHIFT;
    int p = atomicAdd(&cur[k], 1);
    uint2 u;
    u.x = (unsigned)src[e] | ((unsigned)(d & BMASK) << 18);
    u.y = pack2(kw[e], kw[NE + e]);
    stage[p] = u;
    stageK[p] = (unsigned short)k;
  }
  __syncthreads();
  // coalesced write-out
  for (int i = tid; i < EPB; i += 512) {
    int k = stageK[i];
    bsorted[gof[k] + i] = stage[i];
  }
}

// ============ stage 2: two-key counting sort (node, src-slice) ============
// 391 blocks x 512 threads. key = (dst_local<<3)|slice, 4096 LDS bins.
// One histogram pass + hierarchical scan + ONE placement sweep (replaces the
// former 7-pass predicated sweep). Thread t owns node t's 8 bins -> cnt/offs
// fall out of the scan for free. Per-node slice ordering preserved by bin order.

__global__ __launch_bounds__(512) void nsort_kernel(
    const uint2* __restrict__ bsorted, const int* __restrict__ bbase,
    int* __restrict__ cnt, int* __restrict__ offs, uint2* __restrict__ sedge) {
  __shared__ int h4[4096];    // 16 KB
  __shared__ int cur4[4096];  // 16 KB
  __shared__ int s[512];      // 2 KB
  int tid = threadIdx.x, b = blockIdx.x;
  for (int j = tid; j < 4096; j += 512) h4[j] = 0;
  __syncthreads();
  int r0 = bbase[b], r1 = bbase[b + 1];
  int i0 = r0 + tid;

  uint2 e[EMAX];
#pragma unroll
  for (int j = 0; j < EMAX; ++j) {
    int i = i0 + j * 512;
    if (i < r1) {
      e[j] = bsorted[i];
      int key = (int)((e[j].x >> 18) << 3) | (int)((e[j].x & SRCMASK) >> SSHIFT);
      atomicAdd(&h4[key], 1);
    }
  }
  for (int i = i0 + EMAX * 512; i < r1; i += 512) {  // overflow (statistically never)
    unsigned ex = bsorted[i].x;
    int key = (int)((ex >> 18) << 3) | (int)((ex & SRCMASK) >> SSHIFT);
    atomicAdd(&h4[key], 1);
  }
  __syncthreads();

  // hierarchical exclusive scan: thread t owns bins [t*8, t*8+8)
  int loc[8];
  int sum = 0;
#pragma unroll
  for (int k = 0; k < 8; ++k) {
    loc[k] = sum;
    sum += h4[tid * 8 + k];
  }
  s[tid] = sum;
  __syncthreads();
#pragma unroll
  for (int off = 1; off < 512; off <<= 1) {
    int t = (tid >= off) ? s[tid - off] : 0;
    __syncthreads();
    s[tid] += t;
    __syncthreads();
  }
  int nbase = r0 + s[tid] - sum;  // exclusive global offset of node tid's list
  int node = b * 512 + tid;
  if (node < NN) { cnt[node] = sum; offs[node] = nbase; }
#pragma unroll
  for (int k = 0; k < 8; ++k) cur4[tid * 8 + k] = nbase + loc[k];
  __syncthreads();

  // single placement sweep
#pragma unroll
  for (int j = 0; j < EMAX; ++j) {
    int i = i0 + j * 512;
    if (i < r1) {
      int key = (int)((e[j].x >> 18) << 3) | (int)((e[j].x & SRCMASK) >> SSHIFT);
      int pos = atomicAdd(&cur4[key], 1);
      uint2 w; w.x = e[j].x & SRCMASK; w.y = e[j].y;
      sedge[pos] = w;
    }
  }
  for (int i = i0 + EMAX * 512; i < r1; i += 512) {  // overflow
    uint2 u = bsorted[i];
    int key = (int)((u.x >> 18) << 3) | (int)((u.x & SRCMASK) >> SSHIFT);
    int pos = atomicAdd(&cur4[key], 1);
    u.x &= SRCMASK;
    sedge[pos] = u;
  }
}

// ============== fused conv0 + mlp0 + l2norm -> h1 bf16 [N,32] ==============

__global__ __launch_bounds__(256) void fused0_kernel(
    const unsigned short* __restrict__ xbf, const int* __restrict__ offs,
    const int* __restrict__ cnt, const uint2* __restrict__ sedge,
    const float* __restrict__ W0, const float* __restrict__ b0,
    unsigned short* __restrict__ h1bf) {
  __shared__ float w0t[32][16];
  __shared__ float b0s[32];
  int tid = threadIdx.x;
  for (int i = tid; i < 16 * 32; i += 256) {
    int k = i >> 5, j = i & 31;
    w0t[j][k] = W0[i];
  }
  if (tid < 32) b0s[tid] = b0[tid];
  __syncthreads();

  int node = blockIdx.x * 256 + tid;
  if (node >= NN) return;

  int start = offs[node];
  int deg = cnt[node];
  float ha[8], hb[8];
#pragma unroll
  for (int k = 0; k < 8; ++k) { ha[k] = 0.f; hb[k] = 0.f; }

  int i = 0;
  for (; i + 4 <= deg; i += 4) {
    uint2 ee[4];
    uint4 uu[4];
#pragma unroll
    for (int j = 0; j < 4; ++j) ee[j] = sedge[start + i + j];
#pragma unroll
    for (int j = 0; j < 4; ++j)
      uu[j] = *reinterpret_cast<const uint4*>(xbf + (size_t)ee[j].x * 8);
#pragma unroll
    for (int j = 0; j < 4; ++j) acc_edge(ee[j], uu[j], ha, hb);
  }
  for (; i < deg; ++i) {
    uint2 e = sedge[start + i];
    uint4 u = *reinterpret_cast<const uint4*>(xbf + (size_t)e.x * 8);
    acc_edge(e, u, ha, hb);
  }

  float o[32];
  float ss = 0.f;
#pragma unroll
  for (int j = 0; j < 32; ++j) {
    float acc = b0s[j];
#pragma unroll
    for (int k = 0; k < 8; ++k) acc += ha[k] * w0t[j][k];
#pragma unroll
    for (int k = 0; k < 8; ++k) acc += hb[k] * w0t[j][8 + k];
    o[j] = acc;
    ss += acc * acc;
  }
  float inv = 1.f / fmaxf(sqrtf(ss), 1e-12f);
  uint4* op = reinterpret_cast<uint4*>(h1bf + (size_t)node * 32);
#pragma unroll
  for (int c = 0; c < 4; ++c) {
    uint4 u;
    u.x = pack2(o[c * 8 + 0] * inv, o[c * 8 + 1] * inv);
    u.y = pack2(o[c * 8 + 2] * inv, o[c * 8 + 3] * inv);
    u.z = pack2(o[c * 8 + 4] * inv, o[c * 8 + 5] * inv);
    u.w = pack2(o[c * 8 + 6] * inv, o[c * 8 + 7] * inv);
    op[c] = u;
  }
}

// ============== gather1: CSR gather of h1 -> g bf16 [N,64] ==============
// 4 lanes per node; flat loop with manual 8-deep load pipeline.

__global__ __launch_bounds__(256) void gather1_kernel(
    const unsigned short* __restrict__ h1bf, const int* __restrict__ offs,
    const int* __restrict__ cnt, const uint2* __restrict__ sedge,
    unsigned short* __restrict__ gbf) {
  int idx = blockIdx.x * 256 + threadIdx.x;
  int node = idx >> 2, q = idx & 3;   // grid exact: node < NN always
  int start = offs[node];
  int deg = cnt[node];

  float g0[8], g1[8];
#pragma unroll
  for (int k = 0; k < 8; ++k) { g0[k] = 0.f; g1[k] = 0.f; }

  int i = 0;
  for (; i + 8 <= deg; i += 8) {
    uint2 ee[8];
    uint4 uu[8];
#pragma unroll
    for (int j = 0; j < 8; ++j) ee[j] = sedge[start + i + j];
#pragma unroll
    for (int j = 0; j < 8; ++j)
      uu[j] = *reinterpret_cast<const uint4*>(h1bf + (size_t)ee[j].x * 32 + q * 8);
#pragma unroll
    for (int j = 0; j < 8; ++j) acc_edge(ee[j], uu[j], g0, g1);
  }
  for (; i + 4 <= deg; i += 4) {
    uint2 ee[4];
    uint4 uu[4];
#pragma unroll
    for (int j = 0; j < 4; ++j) ee[j] = sedge[start + i + j];
#pragma unroll
    for (int j = 0; j < 4; ++j)
      uu[j] = *reinterpret_cast<const uint4*>(h1bf + (size_t)ee[j].x * 32 + q * 8);
#pragma unroll
    for (int j = 0; j < 4; ++j) acc_edge(ee[j], uu[j], g0, g1);
  }
  for (; i < deg; ++i) {
    uint2 e = sedge[start + i];
    uint4 u = *reinterpret_cast<const uint4*>(h1bf + (size_t)e.x * 32 + q * 8);
    acc_edge(e, u, g0, g1);
  }

  uint4 s0, s1;
  s0.x = pack2(g0[0], g0[1]); s0.y = pack2(g0[2], g0[3]);
  s0.z = pack2(g0[4], g0[5]); s0.w = pack2(g0[6], g0[7]);
  s1.x = pack2(g1[0], g1[1]); s1.y = pack2(g1[2], g1[3]);
  s1.z = pack2(g1[4], g1[5]); s1.w = pack2(g1[6], g1[7]);
  *reinterpret_cast<uint4*>(gbf + (size_t)node * 64 + q * 8) = s0;
  *reinterpret_cast<uint4*>(gbf + (size_t)node * 64 + 32 + q * 8) = s1;
}

// ============== mlp1: MFMA 16x16x32_bf16, 16 nodes per wave-tile ==============
// A: row=lane&15, k=(lane>>4)*8+i ; B: col=lane&15, k=(lane>>4)*8+i
// D: col=lane&15, row=(lane>>4)*4+q   [m89-verified]

__global__ __launch_bounds__(256) void mlp1_kernel(
    const unsigned short* __restrict__ gbf,
    const float* __restrict__ W1, const float* __restrict__ b1,
    const float* __restrict__ W2, const float* __restrict__ b2,
    float* __restrict__ out) {
  __shared__ __align__(16) short hlds[4][16][136];
  int tid = threadIdx.x;
  int wave = tid >> 6, lane = tid & 63;
  int lg = lane >> 4;
  int lr = lane & 15;

  bf16x8 w1f[8][2];
#pragma unroll
  for (int n = 0; n < 8; ++n)
#pragma unroll
    for (int ks = 0; ks < 2; ++ks) {
      bf16x8 f;
#pragma unroll
      for (int i = 0; i < 8; ++i)
        f[i] = (short)f2bfu(W1[(size_t)(ks * 32 + lg * 8 + i) * 128 + n * 16 + lr]);
      w1f[n][ks] = f;
    }
  bf16x8 w2f[4][4];
#pragma unroll
  for (int n2 = 0; n2 < 4; ++n2)
#pragma unroll
    for (int ks = 0; ks < 4; ++ks) {
      bf16x8 f;
#pragma unroll
      for (int i = 0; i < 8; ++i)
        f[i] = (short)f2bfu(W2[(size_t)(ks * 32 + lg * 8 + i) * 64 + n2 * 16 + lr]);
      w2f[n2][ks] = f;
    }
  float b1v[8], b2v[4];
#pragma unroll
  for (int n = 0; n < 8; ++n) b1v[n] = b1[n * 16 + lr];
#pragma unroll
  for (int n2 = 0; n2 < 4; ++n2) b2v[n2] = b2[n2 * 16 + lr];

  for (int tile = blockIdx.x * 4 + wave; tile < NT_MLP1; tile += gridDim.x * 4) {
    int base = tile * 16;
    const bf16x8* grow = reinterpret_cast<const bf16x8*>(gbf + (size_t)(base + lr) * 64);
    bf16x8 a1_0 = grow[lg];
    bf16x8 a1_1 = grow[4 + lg];

#pragma unroll
    for (int n = 0; n < 8; ++n) {
      f32x4 acc = {0.f, 0.f, 0.f, 0.f};
      acc = __builtin_amdgcn_mfma_f32_16x16x32_bf16(a1_0, w1f[n][0], acc, 0, 0, 0);
      acc = __builtin_amdgcn_mfma_f32_16x16x32_bf16(a1_1, w1f[n][1], acc, 0, 0, 0);
#pragma unroll
      for (int q = 0; q < 4; ++q) {
        float v = fmaxf(acc[q] + b1v[n], 0.f);
        hlds[wave][lg * 4 + q][n * 16 + lr] = (short)f2bfu(v);
      }
    }

    bf16x8 a2[4];
#pragma unroll
    for (int ks = 0; ks < 4; ++ks)
      a2[ks] = *reinterpret_cast<const bf16x8*>(&hlds[wave][lr][ks * 32 + lg * 8]);
    f32x4 acc2[4];
#pragma unroll
    for (int n2 = 0; n2 < 4; ++n2) {
      f32x4 a = {0.f, 0.f, 0.f, 0.f};
#pragma unroll
      for (int ks = 0; ks < 4; ++ks)
        a = __builtin_amdgcn_mfma_f32_16x16x32_bf16(a2[ks], w2f[n2][ks], a, 0, 0, 0);
      acc2[n2] = a;
    }

#pragma unroll
    for (int q = 0; q < 4; ++q) {
      float s = 0.f;
#pragma unroll
      for (int n2 = 0; n2 < 4; ++n2) {
        float v = acc2[n2][q] + b2v[n2];
        s += v * v;
      }
      s += __shfl_xor(s, 1); s += __shfl_xor(s, 2);
      s += __shfl_xor(s, 4); s += __shfl_xor(s, 8);
      float inv = 1.f / fmaxf(sqrtf(s), 1e-12f);
      size_t rowoff = (size_t)(base + lg * 4 + q) * 64 + lr;
#pragma unroll
      for (int n2 = 0; n2 < 4; ++n2)
        out[rowoff + n2 * 16] = (acc2[n2][q] + b2v[n2]) * inv;
    }
  }
}

// ======================= launch =======================

extern "C" void kernel_launch(void* const* d_in, const int* in_sizes, int n_in,
                              void* d_out, int out_size, void* d_ws, size_t ws_size,
                              hipStream_t stream) {
  const float* x  = (const float*)d_in[0];
  const int* ei   = (const int*)d_in[1];
  const float* kw = (const float*)d_in[2];
  const float* W0 = (const float*)d_in[3];
  const float* b0 = (const float*)d_in[4];
  const float* W1 = (const float*)d_in[5];
  const float* b1 = (const float*)d_in[6];
  const float* W2 = (const float*)d_in[7];
  const float* b2 = (const float*)d_in[8];
  float* out = (float*)d_out;

  const int* src = ei;
  const int* dst = ei + NE;

  // ws layout, ~72 MB:
  char* p = (char*)d_ws;
  uint2* bsorted = (uint2*)p;                p += (size_t)NE * 8;            // 25.6 MB
  uint2* sedge   = (uint2*)p;                p += (size_t)NE * 8;            // 25.6 MB
  unsigned short* h1bf = (unsigned short*)p; p += (size_t)NN * 32 * 2;       // 12.8 MB
  unsigned short* xbf  = (unsigned short*)p; p += (size_t)NN * 8 * 2;        // 3.2 MB
  int* bhT   = (int*)p;                      p += (size_t)NBUCK * NBLK_A * 4;// 1.6 MB
  int* bhE   = (int*)p;                      p += (size_t)NBUCK * NBLK_A * 4;// 1.6 MB
  int* btot  = (int*)p;                      p += (size_t)NBUCK * 4;
  int* bbase = (int*)p;                      p += (size_t)(NBUCK + 1) * 4;
  int* cnt   = (int*)p;                      p += (size_t)NN * 4;            // 0.8 MB
  int* offs  = (int*)p;                      p += (size_t)NN * 4;            // 0.8 MB
  // gbf reuses bsorted (dead after nsort); NN*64*2 == NE*8 bytes exactly.
  unsigned short* gbf = (unsigned short*)bsorted;

  bhist_kernel<<<NBLK_A, 256, 0, stream>>>(dst, bhT, x, xbf);
  bscan_kernel<<<NBUCK, NBLK_A, 0, stream>>>(bhT, bhE, btot);
  bbase_kernel<<<1, 512, 0, stream>>>(btot, bbase);
  bplace_kernel<<<NBLK_A, 512, 0, stream>>>(src, dst, kw, bhT, bhE, bbase, bsorted);

  nsort_kernel<<<NBUCK, 512, 0, stream>>>(bsorted, bbase, cnt, offs, sedge);

  fused0_kernel<<<NB_SCAN, 256, 0, stream>>>(xbf, offs, cnt, sedge, W0, b0, h1bf);
  gather1_kernel<<<(4 * NN) / 256, 256, 0, stream>>>(h1bf, offs, cnt, sedge, gbf);
  mlp1_kernel<<<768, 256, 0, stream>>>(gbf, W1, b1, W2, b2, out);
}